// Round 13
// baseline (280.790 us; speedup 1.0000x reference)
//
#include <hip/hip_runtime.h>

#define D_IN  256
#define D_HID 512
#define NEG_SLOPE 0.2f
#define CAP 32                 // bucket = 32 x u16 = 64 B = ONE cache line -> L2-resident
                               // P(deg>32) ~ 1e-3 at lambda=16 -> ~50 spill nodes, ovf path
#define OVF_MAX 65536

typedef __attribute__((ext_vector_type(8))) short short8;
typedef __attribute__((ext_vector_type(4))) float floatx4;

__device__ __forceinline__ unsigned short f2bf(float f) {
    unsigned int u = __float_as_uint(f);
    u += 0x7fffu + ((u >> 16) & 1u);   // round-to-nearest-even
    return (unsigned short)(u >> 16);
}
__device__ __forceinline__ float bf2f(unsigned short u) {
    return __uint_as_float(((unsigned int)u) << 16);
}

__device__ __forceinline__ int eidx(const void* ei, long pos, int is64) {
    return is64 ? (int)((const long long*)ei)[pos] : ((const int*)ei)[pos];
}

// ---- merged init+degfill: blocks [0,FB) run the degfill atomic pass (long-latency,
//      launched first); blocks [FB,FB+96) do weight transposes; the rest stream
//      x->bf16 and seed out=b_out. deg/ovfcnt pre-zeroed via hipMemsetAsync.
//      esrc buckets are u16[32] = one 64B line -> write-combining in L2 (the CAP=64
//      int version thrashed per-XCD L2 and wrote back 48MB of scatter lines). ----
__global__ __launch_bounds__(256) void k_initfill(const float* __restrict__ x,
                                                  unsigned short* __restrict__ xb,
                                                  int* __restrict__ deg, int N,
                                                  const void* __restrict__ ei, int E,
                                                  int npairs,
                                                  unsigned short* __restrict__ esrc,
                                                  int2* __restrict__ ovf,
                                                  int* __restrict__ ovfcnt,
                                                  const float* __restrict__ b_out,
                                                  float* __restrict__ out,
                                                  const float* __restrict__ Wa,
                                                  unsigned short* __restrict__ Wat,
                                                  const float* __restrict__ Wb,
                                                  unsigned short* __restrict__ Wbt,
                                                  long xthreads, int FB) {
    __shared__ float tl[64][65];
    int b = blockIdx.x;
    if (b < FB) {                      // degfill: deg-count + direct bucket scatter
        __shared__ int nz;
        if (threadIdx.x == 0) nz = 0;
        __syncthreads();
        const unsigned int* eu = (const unsigned int*)ei;
        for (int p = threadIdx.x; p < npairs; p += 256)
            if (eu[2 * p + 1] != 0) nz = 1;
        __syncthreads();
        int is64 = nz ? 0 : 1;
        int e = b * 256 + threadIdx.x;
        if (e >= E) return;
        int s = eidx(ei, e, is64), d = eidx(ei, (long)E + e, is64);
        int r = atomicAdd(&deg[d], 1);
        if (r < CAP) {
            esrc[d * CAP + r] = (unsigned short)s;   // N=50000 < 65536
        } else {
            int p = atomicAdd(ovfcnt, 1);
            if (p < OVF_MAX) ovf[p] = make_int2(d, s);
        }
        return;
    }
    b -= FB;
    if (b < 96) {                      // weight transpose, coalesced both ways
        const float* W; unsigned short* Wt; int K, Nc, tk, tn;
        if (b < 32) { W = Wa; Wt = Wat; K = 256; Nc = 512; tk = b & 3; tn = b >> 2; }
        else { b -= 32; W = Wb; Wt = Wbt; K = 512; Nc = 512; tk = b & 7; tn = b >> 3; }
        int k0 = tk * 64, n0 = tn * 64;
        int c = threadIdx.x & 63;
        int r0 = threadIdx.x >> 6;
#pragma unroll
        for (int i = 0; i < 16; ++i) {
            int r = r0 + i * 4;
            tl[r][c] = W[(long)(k0 + r) * Nc + n0 + c];
        }
        __syncthreads();
#pragma unroll
        for (int i = 0; i < 16; ++i) {
            int r = r0 + i * 4;
            Wt[(long)(n0 + r) * K + k0 + c] = f2bf(tl[c][r]);
        }
        return;
    }
    long t = (long)(b - 96) * 256 + threadIdx.x;
    if (t < xthreads) {                // 1 thread = 4 floats
        long i = t * 4;
        float4 v = *(const float4*)(x + i);
        ushort4 o;
        o.x = f2bf(v.x); o.y = f2bf(v.y); o.z = f2bf(v.z); o.w = f2bf(v.w);
        *(ushort4*)(xb + i) = o;
    }
    if (t < N) out[t] = b_out[0];      // gemm2f atomically adds on top
}

// ---- gather: wave=node, u16 bucketed edges; dinv on the fly (rsqrt of deg) ----
__global__ __launch_bounds__(256) void k_gather(const unsigned short* __restrict__ xb,
                                                const int* __restrict__ deg,
                                                const unsigned short* __restrict__ esrc,
                                                const int2* __restrict__ ovf,
                                                const int* __restrict__ ovfcnt,
                                                unsigned short* __restrict__ aggb, int N) {
    int node = blockIdx.x * 4 + (threadIdx.x >> 6);
    int lane = threadIdx.x & 63;
    if (node >= N) return;
    int half = lane >> 5;
    int li   = lane & 31;
    int colofs = li * 8;
    int dn = deg[node];
    float di = rsqrtf(1.0f + (float)dn);

    float a[8];
    {
        short8 v = *(const short8*)(xb + (long)node * D_IN + colofs);
#pragma unroll
        for (int j = 0; j < 8; ++j)
            a[j] = (half == 0) ? di * bf2f((unsigned short)v[j]) : 0.f;
    }

    int cnt = dn > CAP ? CAP : dn;
    int beg = node * CAP, end = beg + cnt;
    int e = beg;
    for (; e + 8 <= end; e += 8) {      // 4 x 1KB wave-loads in flight
        int s0 = esrc[e + half];
        int s1 = esrc[e + 2 + half];
        int s2 = esrc[e + 4 + half];
        int s3 = esrc[e + 6 + half];
        float w0 = rsqrtf(1.0f + (float)deg[s0]);
        float w1 = rsqrtf(1.0f + (float)deg[s1]);
        float w2 = rsqrtf(1.0f + (float)deg[s2]);
        float w3 = rsqrtf(1.0f + (float)deg[s3]);
        short8 u0 = *(const short8*)(xb + (long)s0 * D_IN + colofs);
        short8 u1 = *(const short8*)(xb + (long)s1 * D_IN + colofs);
        short8 u2 = *(const short8*)(xb + (long)s2 * D_IN + colofs);
        short8 u3 = *(const short8*)(xb + (long)s3 * D_IN + colofs);
#pragma unroll
        for (int j = 0; j < 8; ++j)
            a[j] += w0 * bf2f((unsigned short)u0[j]) + w1 * bf2f((unsigned short)u1[j])
                  + w2 * bf2f((unsigned short)u2[j]) + w3 * bf2f((unsigned short)u3[j]);
    }
    for (; e < end; e += 2) {
        int j0 = e + half;
        int jj = (j0 < end) ? j0 : end - 1;
        int s = esrc[jj];
        float w = (j0 < end) ? rsqrtf(1.0f + (float)deg[s]) : 0.f;
        short8 u = *(const short8*)(xb + (long)s * D_IN + colofs);
#pragma unroll
        for (int j = 0; j < 8; ++j)
            a[j] += w * bf2f((unsigned short)u[j]);
    }

    // overflow edges (deg>CAP spill; ~50-100 entries, L2-hot scan)
    int oc = *ovfcnt;
    if (oc > OVF_MAX) oc = OVF_MAX;
    for (int i = 0; i < oc; ++i) {
        int2 p = ovf[i];
        if (p.x == node && half == 0) {
            float w = rsqrtf(1.0f + (float)deg[p.y]);
            short8 u = *(const short8*)(xb + (long)p.y * D_IN + colofs);
#pragma unroll
            for (int j = 0; j < 8; ++j)
                a[j] += w * bf2f((unsigned short)u[j]);
        }
    }

#pragma unroll
    for (int j = 0; j < 8; ++j) a[j] += __shfl_xor(a[j], 32, 64);

    if (half == 0) {
        short8 o;
#pragma unroll
        for (int j = 0; j < 8; ++j) o[j] = (short)f2bf(a[j] * di);
        *(short8*)(aggb + (long)node * D_IN + colofs) = o;
    }
}

// ============ BK=64 swizzled-LDS 128x128 GEMM, counted-vmcnt 2-deep pipeline ======
__device__ __forceinline__ void async_cp16(const unsigned short* gp, unsigned short* lp) {
    __builtin_amdgcn_global_load_lds((const __attribute__((address_space(1))) void*)gp,
                                     (__attribute__((address_space(3))) void*)lp, 16, 0, 0);
}

__device__ __forceinline__ void stage_sw64(const unsigned short* src, int strideK,
                                           int rowMax, unsigned short* lds, int tid) {
#pragma unroll
    for (int rr = 0; rr < 4; ++rr) {
        int c = rr * 256 + tid;          // 0..1023 16B chunks
        int row = c >> 3;
        int ci = (c & 7) ^ (row & 7);    // logical chunk stored at this slot
        if (row > rowMax) row = rowMax;
        async_cp16(src + (long)row * strideK + ci * 8, lds + c * 8);
    }
}

__device__ __forceinline__ bool map_block(int b, int M, int& m0, int& n0) {
    int x = b & 7, slot = b >> 3;
    int mt = x + 8 * (slot >> 2);
    m0 = mt * 128; n0 = (slot & 3) * 128;
    return m0 < M;
}

__device__ __forceinline__ void mfma_step(const unsigned short* As_,
                                          const unsigned short* Bs_,
                                          floatx4 acc[4][4],
                                          int wm, int wn, int r, int q, int xv) {
#pragma unroll
    for (int s = 0; s < 2; ++s) {        // two K=32 sub-steps per tile
        int slotbase = s * 4 + q;
        short8 af[4], bf[4];
#pragma unroll
        for (int i = 0; i < 4; ++i)
            af[i] = *(const short8*)(As_ + (wm + i * 16 + r) * 64 + (slotbase ^ xv) * 8);
#pragma unroll
        for (int j = 0; j < 4; ++j)
            bf[j] = *(const short8*)(Bs_ + (wn + j * 16 + r) * 64 + (slotbase ^ xv) * 8);
#pragma unroll
        for (int i = 0; i < 4; ++i)
#pragma unroll
            for (int j = 0; j < 4; ++j)
                acc[i][j] = __builtin_amdgcn_mfma_f32_16x16x32_bf16(af[i], bf[j], acc[i][j], 0, 0, 0);
    }
}

// K-loop body shared by both GEMMs. 8 global_load_lds per thread per tile:
// vmcnt(8) == "my older tile has fully landed".
#define GEMM_KLOOP(Ab, Bb, K, rmA)                                              \
    const int nt = (K) >> 6;                                                    \
    stage_sw64((Ab), (K), (rmA), As[0], tid);                                   \
    stage_sw64((Bb), (K), 127, Bs[0], tid);                                     \
    if (nt > 1) {                                                               \
        stage_sw64((Ab) + 64, (K), (rmA), As[1], tid);                          \
        stage_sw64((Bb) + 64, (K), 127, Bs[1], tid);                            \
    }                                                                           \
    for (int t = 0; t < nt; ++t) {                                              \
        const int cur = t & 1;                                                  \
        if (t + 1 < nt) asm volatile("s_waitcnt vmcnt(8)" ::: "memory");        \
        else            asm volatile("s_waitcnt vmcnt(0)" ::: "memory");        \
        __builtin_amdgcn_sched_barrier(0);                                      \
        __builtin_amdgcn_s_barrier();                                           \
        __builtin_amdgcn_sched_barrier(0);                                      \
        mfma_step(As[cur], Bs[cur], acc, wm, wn, r, q, xv);                     \
        __builtin_amdgcn_sched_barrier(0);                                      \
        __builtin_amdgcn_s_barrier();                                           \
        __builtin_amdgcn_sched_barrier(0);                                      \
        if (t + 2 < nt) {                                                       \
            stage_sw64((Ab) + (long)(t + 2) * 64, (K), (rmA), As[cur], tid);    \
            stage_sw64((Bb) + (long)(t + 2) * 64, (K), 127, Bs[cur], tid);      \
        }                                                                       \
    }

// ---- GEMM1: C[M,512] = bf16(leaky(A[M,K] @ Bt[512,K]^T + bias)), LDS-staged store ----
__global__ __launch_bounds__(256) void k_gemm_bf16(const unsigned short* __restrict__ A,
                                                   const unsigned short* __restrict__ Bt,
                                                   const float* __restrict__ bias,
                                                   unsigned short* __restrict__ C,
                                                   int M, int K) {
    __shared__ __align__(16) unsigned short As[2][128 * 64];   // 32 KB
    __shared__ __align__(16) unsigned short Bs[2][128 * 64];   // 32 KB
    __shared__ __align__(16) unsigned short Ep[32 * 128];      // epilogue staging, 8 KB
    const int tid  = threadIdx.x;
    const int lane = tid & 63, wave = tid >> 6;
    int m0, n0;
    if (!map_block(blockIdx.x, M, m0, n0)) return;
    const int r = lane & 15, q = lane >> 4;
    const int xv = r & 7;
    const int wm = (wave & 1) * 64, wn = (wave >> 1) * 64;
    const int band = wm >> 6;
    const int rmA = M - 1 - m0;
    const unsigned short* Ab = A + (long)m0 * K;
    const unsigned short* Bb = Bt + (long)n0 * K;

    floatx4 acc[4][4];
#pragma unroll
    for (int i = 0; i < 4; ++i)
#pragma unroll
        for (int j = 0; j < 4; ++j) acc[i][j] = (floatx4){0.f, 0.f, 0.f, 0.f};

    GEMM_KLOOP(Ab, Bb, K, rmA)

    // epilogue: per i-band, stage 32 rows x 128 cols bf16 in LDS, then 16B/lane stores
    float bv[4];
#pragma unroll
    for (int j = 0; j < 4; ++j) bv[j] = bias[n0 + wn + j * 16 + r];

#pragma unroll
    for (int i = 0; i < 4; ++i) {
#pragma unroll
        for (int j = 0; j < 4; ++j) {
#pragma unroll
            for (int t2 = 0; t2 < 4; ++t2) {
                float v = acc[i][j][t2] + bv[j];
                v = v > 0.f ? v : NEG_SLOPE * v;
                Ep[(band * 16 + q * 4 + t2) * 128 + wn + j * 16 + r] = f2bf(v);
            }
        }
        __syncthreads();
#pragma unroll
        for (int rr = 0; rr < 2; ++rr) {
            int c = rr * 256 + tid;
            int lrow = c >> 4, ccol = c & 15;
            int grow = m0 + (lrow >> 4) * 64 + i * 16 + (lrow & 15);
            if (grow < M) {
                short8 v = *(const short8*)(Ep + lrow * 128 + ccol * 8);
                *(short8*)(C + (long)grow * D_HID + n0 + ccol * 8) = v;
            }
        }
        __syncthreads();
    }
}

// ---- GEMM2 fused with head: out[row] += sum_col leaky(A@Bt^T + b2) * wout[col] ----
__global__ __launch_bounds__(256) void k_gemm2f(const unsigned short* __restrict__ A,
                                                const unsigned short* __restrict__ Bt,
                                                const float* __restrict__ bias,
                                                const float* __restrict__ wout,
                                                float* __restrict__ out,
                                                int M, int K) {
    __shared__ __align__(16) unsigned short As[2][128 * 64];
    __shared__ __align__(16) unsigned short Bs[2][128 * 64];
    const int tid  = threadIdx.x;
    const int lane = tid & 63, wave = tid >> 6;
    int m0, n0;
    if (!map_block(blockIdx.x, M, m0, n0)) return;
    const int r = lane & 15, q = lane >> 4;
    const int xv = r & 7;
    const int wm = (wave & 1) * 64, wn = (wave >> 1) * 64;
    const int rmA = M - 1 - m0;
    const unsigned short* Ab = A + (long)m0 * K;
    const unsigned short* Bb = Bt + (long)n0 * K;

    floatx4 acc[4][4];
#pragma unroll
    for (int i = 0; i < 4; ++i)
#pragma unroll
        for (int j = 0; j < 4; ++j) acc[i][j] = (floatx4){0.f, 0.f, 0.f, 0.f};

    GEMM_KLOOP(Ab, Bb, K, rmA)

    float bv[4], wv[4];
#pragma unroll
    for (int j = 0; j < 4; ++j) {
        int col = n0 + wn + j * 16 + r;
        bv[j] = bias[col];
        wv[j] = wout[col];
    }
#pragma unroll
    for (int i = 0; i < 4; ++i) {
#pragma unroll
        for (int t2 = 0; t2 < 4; ++t2) {
            float p = 0.f;
#pragma unroll
            for (int j = 0; j < 4; ++j) {
                float v = acc[i][j][t2] + bv[j];
                v = v > 0.f ? v : NEG_SLOPE * v;
                p += v * wv[j];
            }
            p += __shfl_xor(p, 8, 64);
            p += __shfl_xor(p, 4, 64);
            p += __shfl_xor(p, 2, 64);
            p += __shfl_xor(p, 1, 64);
            if (r == 0) {
                int row = m0 + wm + i * 16 + q * 4 + t2;
                if (row < M) atomicAdd(&out[row], p);   // out pre-seeded with b_out
            }
        }
    }
}

extern "C" void kernel_launch(void* const* d_in, const int* in_sizes, int n_in,
                              void* d_out, int out_size, void* d_ws, size_t ws_size,
                              hipStream_t stream) {
    const float* x     = (const float*)d_in[0];
    const void*  ei    = d_in[1];
    const float* W_gcn = (const float*)d_in[2];
    const float* b_gcn = (const float*)d_in[3];
    const float* W2    = (const float*)d_in[4];
    const float* b2    = (const float*)d_in[5];
    const float* W_out = (const float*)d_in[6];
    const float* b_out = (const float*)d_in[7];
    float* out = (float*)d_out;

    const int N = in_sizes[0] / D_IN;
    const int E = in_sizes[1] / 2;

    char* w = (char*)d_ws;
    size_t off = 0;
    auto alloc = [&](size_t bytes) { char* p = w + off; off = (off + bytes + 255) & ~(size_t)255; return p; };
    int*            ovfcnt = (int*)alloc(256);
    int*            deg_i  = (int*)alloc((size_t)N * 4);
    int2*           ovf    = (int2*)alloc((size_t)OVF_MAX * 8);
    unsigned short* esrc   = (unsigned short*)alloc((size_t)N * CAP * 2);
    unsigned short* xb     = (unsigned short*)alloc((size_t)N * D_IN * 2);
    unsigned short* aggb   = (unsigned short*)alloc((size_t)N * D_IN * 2);
    unsigned short* h1     = (unsigned short*)alloc((size_t)N * D_HID * 2);
    unsigned short* Wgt    = (unsigned short*)alloc((size_t)D_IN * D_HID * 2);
    unsigned short* W2t    = (unsigned short*)alloc((size_t)D_HID * D_HID * 2);

    hipMemsetAsync(deg_i, 0, (size_t)N * 4, stream);
    hipMemsetAsync(ovfcnt, 0, 4, stream);

    int npairs = E < 2048 ? E : 2048;
    long xthreads = (long)N * D_IN / 4;
    int FB = (E + 255) / 256;
    int init_blocks = FB + 96 + (int)((xthreads + 255) / 256);
    k_initfill<<<init_blocks, 256, 0, stream>>>(x, xb, deg_i, N, ei, E, npairs,
                                                esrc, ovf, ovfcnt, b_out, out,
                                                W_gcn, Wgt, W2, W2t, xthreads, FB);

    k_gather<<<(N + 3) / 4, 256, 0, stream>>>(xb, deg_i, esrc, ovf, ovfcnt, aggb, N);

    int mtiles = (N + 127) / 128;
    int gblocks = ((mtiles + 7) / 8) * 8 * 4;
    k_gemm_bf16<<<gblocks, 256, 0, stream>>>(aggb, Wgt, b_gcn, h1, N, D_IN);
    k_gemm2f<<<gblocks, 256, 0, stream>>>(h1, W2t, b2, W_out, out, N, D_HID);
}

// Round 14
// 275.240 us; speedup vs baseline: 1.0202x; 1.0202x over previous
//
#include <hip/hip_runtime.h>

#define D_IN  256
#define D_HID 512
#define NEG_SLOPE 0.2f
#define CAP 64                 // bucket = 64 x u16 = 128 B = 2 lines; P(deg>64) ~ e^-42
                               // -> ovf stays EMPTY (round-13's CAP=32 spilled ~100 entries
                               //    and every gather wave scanned them: +3.8us)
#define OVF_MAX 65536

typedef __attribute__((ext_vector_type(8))) short short8;
typedef __attribute__((ext_vector_type(4))) float floatx4;

__device__ __forceinline__ unsigned short f2bf(float f) {
    unsigned int u = __float_as_uint(f);
    u += 0x7fffu + ((u >> 16) & 1u);   // round-to-nearest-even
    return (unsigned short)(u >> 16);
}
__device__ __forceinline__ float bf2f(unsigned short u) {
    return __uint_as_float(((unsigned int)u) << 16);
}

__device__ __forceinline__ int eidx(const void* ei, long pos, int is64) {
    return is64 ? (int)((const long long*)ei)[pos] : ((const int*)ei)[pos];
}

// ---- merged init+degfill: blocks [0,FB) run the degfill atomic pass (long-latency,
//      launched first); blocks [FB,FB+96) do weight transposes; the rest stream
//      x->bf16 and seed out=b_out. deg/ovfcnt pre-zeroed via hipMemsetAsync.
//      esrc buckets are u16[64] = two 64B lines; total footprint 6.4MB -> mostly
//      L2-resident scatter (int CAP=64 was 12.8MB and thrashed: 48MB write-back). ----
__global__ __launch_bounds__(256) void k_initfill(const float* __restrict__ x,
                                                  unsigned short* __restrict__ xb,
                                                  int* __restrict__ deg, int N,
                                                  const void* __restrict__ ei, int E,
                                                  int npairs,
                                                  unsigned short* __restrict__ esrc,
                                                  int2* __restrict__ ovf,
                                                  int* __restrict__ ovfcnt,
                                                  const float* __restrict__ b_out,
                                                  float* __restrict__ out,
                                                  const float* __restrict__ Wa,
                                                  unsigned short* __restrict__ Wat,
                                                  const float* __restrict__ Wb,
                                                  unsigned short* __restrict__ Wbt,
                                                  long xthreads, int FB) {
    __shared__ float tl[64][65];
    int b = blockIdx.x;
    if (b < FB) {                      // degfill: deg-count + direct bucket scatter
        __shared__ int nz;
        if (threadIdx.x == 0) nz = 0;
        __syncthreads();
        const unsigned int* eu = (const unsigned int*)ei;
        for (int p = threadIdx.x; p < npairs; p += 256)
            if (eu[2 * p + 1] != 0) nz = 1;
        __syncthreads();
        int is64 = nz ? 0 : 1;
        int e = b * 256 + threadIdx.x;
        if (e >= E) return;
        int s = eidx(ei, e, is64), d = eidx(ei, (long)E + e, is64);
        int r = atomicAdd(&deg[d], 1);
        if (r < CAP) {
            esrc[d * CAP + r] = (unsigned short)s;   // N=50000 < 65536
        } else {
            int p = atomicAdd(ovfcnt, 1);
            if (p < OVF_MAX) ovf[p] = make_int2(d, s);
        }
        return;
    }
    b -= FB;
    if (b < 96) {                      // weight transpose, coalesced both ways
        const float* W; unsigned short* Wt; int K, Nc, tk, tn;
        if (b < 32) { W = Wa; Wt = Wat; K = 256; Nc = 512; tk = b & 3; tn = b >> 2; }
        else { b -= 32; W = Wb; Wt = Wbt; K = 512; Nc = 512; tk = b & 7; tn = b >> 3; }
        int k0 = tk * 64, n0 = tn * 64;
        int c = threadIdx.x & 63;
        int r0 = threadIdx.x >> 6;
#pragma unroll
        for (int i = 0; i < 16; ++i) {
            int r = r0 + i * 4;
            tl[r][c] = W[(long)(k0 + r) * Nc + n0 + c];
        }
        __syncthreads();
#pragma unroll
        for (int i = 0; i < 16; ++i) {
            int r = r0 + i * 4;
            Wt[(long)(n0 + r) * K + k0 + c] = f2bf(tl[c][r]);
        }
        return;
    }
    long t = (long)(b - 96) * 256 + threadIdx.x;
    if (t < xthreads) {                // 1 thread = 4 floats
        long i = t * 4;
        float4 v = *(const float4*)(x + i);
        ushort4 o;
        o.x = f2bf(v.x); o.y = f2bf(v.y); o.z = f2bf(v.z); o.w = f2bf(v.w);
        *(ushort4*)(xb + i) = o;
    }
    if (t < N) out[t] = b_out[0];      // gemm2f atomically adds on top
}

// ---- gather: wave=node, u16 bucketed edges; dinv on the fly (rsqrt of deg) ----
__global__ __launch_bounds__(256) void k_gather(const unsigned short* __restrict__ xb,
                                                const int* __restrict__ deg,
                                                const unsigned short* __restrict__ esrc,
                                                const int2* __restrict__ ovf,
                                                const int* __restrict__ ovfcnt,
                                                unsigned short* __restrict__ aggb, int N) {
    int node = blockIdx.x * 4 + (threadIdx.x >> 6);
    int lane = threadIdx.x & 63;
    if (node >= N) return;
    int half = lane >> 5;
    int li   = lane & 31;
    int colofs = li * 8;
    int dn = deg[node];
    float di = rsqrtf(1.0f + (float)dn);

    float a[8];
    {
        short8 v = *(const short8*)(xb + (long)node * D_IN + colofs);
#pragma unroll
        for (int j = 0; j < 8; ++j)
            a[j] = (half == 0) ? di * bf2f((unsigned short)v[j]) : 0.f;
    }

    int cnt = dn > CAP ? CAP : dn;
    int beg = node * CAP, end = beg + cnt;
    int e = beg;
    for (; e + 8 <= end; e += 8) {      // 4 x 1KB wave-loads in flight
        int s0 = esrc[e + half];
        int s1 = esrc[e + 2 + half];
        int s2 = esrc[e + 4 + half];
        int s3 = esrc[e + 6 + half];
        float w0 = rsqrtf(1.0f + (float)deg[s0]);
        float w1 = rsqrtf(1.0f + (float)deg[s1]);
        float w2 = rsqrtf(1.0f + (float)deg[s2]);
        float w3 = rsqrtf(1.0f + (float)deg[s3]);
        short8 u0 = *(const short8*)(xb + (long)s0 * D_IN + colofs);
        short8 u1 = *(const short8*)(xb + (long)s1 * D_IN + colofs);
        short8 u2 = *(const short8*)(xb + (long)s2 * D_IN + colofs);
        short8 u3 = *(const short8*)(xb + (long)s3 * D_IN + colofs);
#pragma unroll
        for (int j = 0; j < 8; ++j)
            a[j] += w0 * bf2f((unsigned short)u0[j]) + w1 * bf2f((unsigned short)u1[j])
                  + w2 * bf2f((unsigned short)u2[j]) + w3 * bf2f((unsigned short)u3[j]);
    }
    for (; e < end; e += 2) {
        int j0 = e + half;
        int jj = (j0 < end) ? j0 : end - 1;
        int s = esrc[jj];
        float w = (j0 < end) ? rsqrtf(1.0f + (float)deg[s]) : 0.f;
        short8 u = *(const short8*)(xb + (long)s * D_IN + colofs);
#pragma unroll
        for (int j = 0; j < 8; ++j)
            a[j] += w * bf2f((unsigned short)u[j]);
    }

    // overflow edges (correctness path; EMPTY at CAP=64 -> one scalar load)
    int oc = *ovfcnt;
    if (oc > OVF_MAX) oc = OVF_MAX;
    for (int i = 0; i < oc; ++i) {
        int2 p = ovf[i];
        if (p.x == node && half == 0) {
            float w = rsqrtf(1.0f + (float)deg[p.y]);
            short8 u = *(const short8*)(xb + (long)p.y * D_IN + colofs);
#pragma unroll
            for (int j = 0; j < 8; ++j)
                a[j] += w * bf2f((unsigned short)u[j]);
        }
    }

#pragma unroll
    for (int j = 0; j < 8; ++j) a[j] += __shfl_xor(a[j], 32, 64);

    if (half == 0) {
        short8 o;
#pragma unroll
        for (int j = 0; j < 8; ++j) o[j] = (short)f2bf(a[j] * di);
        *(short8*)(aggb + (long)node * D_IN + colofs) = o;
    }
}

// ============ BK=64 swizzled-LDS 128x128 GEMM, counted-vmcnt 2-deep pipeline ======
__device__ __forceinline__ void async_cp16(const unsigned short* gp, unsigned short* lp) {
    __builtin_amdgcn_global_load_lds((const __attribute__((address_space(1))) void*)gp,
                                     (__attribute__((address_space(3))) void*)lp, 16, 0, 0);
}

__device__ __forceinline__ void stage_sw64(const unsigned short* src, int strideK,
                                           int rowMax, unsigned short* lds, int tid) {
#pragma unroll
    for (int rr = 0; rr < 4; ++rr) {
        int c = rr * 256 + tid;          // 0..1023 16B chunks
        int row = c >> 3;
        int ci = (c & 7) ^ (row & 7);    // logical chunk stored at this slot
        if (row > rowMax) row = rowMax;
        async_cp16(src + (long)row * strideK + ci * 8, lds + c * 8);
    }
}

__device__ __forceinline__ bool map_block(int b, int M, int& m0, int& n0) {
    int x = b & 7, slot = b >> 3;
    int mt = x + 8 * (slot >> 2);
    m0 = mt * 128; n0 = (slot & 3) * 128;
    return m0 < M;
}

__device__ __forceinline__ void mfma_step(const unsigned short* As_,
                                          const unsigned short* Bs_,
                                          floatx4 acc[4][4],
                                          int wm, int wn, int r, int q, int xv) {
#pragma unroll
    for (int s = 0; s < 2; ++s) {        // two K=32 sub-steps per tile
        int slotbase = s * 4 + q;
        short8 af[4], bf[4];
#pragma unroll
        for (int i = 0; i < 4; ++i)
            af[i] = *(const short8*)(As_ + (wm + i * 16 + r) * 64 + (slotbase ^ xv) * 8);
#pragma unroll
        for (int j = 0; j < 4; ++j)
            bf[j] = *(const short8*)(Bs_ + (wn + j * 16 + r) * 64 + (slotbase ^ xv) * 8);
#pragma unroll
        for (int i = 0; i < 4; ++i)
#pragma unroll
            for (int j = 0; j < 4; ++j)
                acc[i][j] = __builtin_amdgcn_mfma_f32_16x16x32_bf16(af[i], bf[j], acc[i][j], 0, 0, 0);
    }
}

// K-loop body shared by both GEMMs. 8 global_load_lds per thread per tile:
// vmcnt(8) == "my older tile has fully landed".
#define GEMM_KLOOP(Ab, Bb, K, rmA)                                              \
    const int nt = (K) >> 6;                                                    \
    stage_sw64((Ab), (K), (rmA), As[0], tid);                                   \
    stage_sw64((Bb), (K), 127, Bs[0], tid);                                     \
    if (nt > 1) {                                                               \
        stage_sw64((Ab) + 64, (K), (rmA), As[1], tid);                          \
        stage_sw64((Bb) + 64, (K), 127, Bs[1], tid);                            \
    }                                                                           \
    for (int t = 0; t < nt; ++t) {                                              \
        const int cur = t & 1;                                                  \
        if (t + 1 < nt) asm volatile("s_waitcnt vmcnt(8)" ::: "memory");        \
        else            asm volatile("s_waitcnt vmcnt(0)" ::: "memory");        \
        __builtin_amdgcn_sched_barrier(0);                                      \
        __builtin_amdgcn_s_barrier();                                           \
        __builtin_amdgcn_sched_barrier(0);                                      \
        mfma_step(As[cur], Bs[cur], acc, wm, wn, r, q, xv);                     \
        __builtin_amdgcn_sched_barrier(0);                                      \
        __builtin_amdgcn_s_barrier();                                           \
        __builtin_amdgcn_sched_barrier(0);                                      \
        if (t + 2 < nt) {                                                       \
            stage_sw64((Ab) + (long)(t + 2) * 64, (K), (rmA), As[cur], tid);    \
            stage_sw64((Bb) + (long)(t + 2) * 64, (K), 127, Bs[cur], tid);      \
        }                                                                       \
    }

// ---- GEMM1: C[M,512] = bf16(leaky(A[M,K] @ Bt[512,K]^T + bias)), LDS-staged store ----
__global__ __launch_bounds__(256) void k_gemm_bf16(const unsigned short* __restrict__ A,
                                                   const unsigned short* __restrict__ Bt,
                                                   const float* __restrict__ bias,
                                                   unsigned short* __restrict__ C,
                                                   int M, int K) {
    __shared__ __align__(16) unsigned short As[2][128 * 64];   // 32 KB
    __shared__ __align__(16) unsigned short Bs[2][128 * 64];   // 32 KB
    __shared__ __align__(16) unsigned short Ep[32 * 128];      // epilogue staging, 8 KB
    const int tid  = threadIdx.x;
    const int lane = tid & 63, wave = tid >> 6;
    int m0, n0;
    if (!map_block(blockIdx.x, M, m0, n0)) return;
    const int r = lane & 15, q = lane >> 4;
    const int xv = r & 7;
    const int wm = (wave & 1) * 64, wn = (wave >> 1) * 64;
    const int band = wm >> 6;
    const int rmA = M - 1 - m0;
    const unsigned short* Ab = A + (long)m0 * K;
    const unsigned short* Bb = Bt + (long)n0 * K;

    floatx4 acc[4][4];
#pragma unroll
    for (int i = 0; i < 4; ++i)
#pragma unroll
        for (int j = 0; j < 4; ++j) acc[i][j] = (floatx4){0.f, 0.f, 0.f, 0.f};

    GEMM_KLOOP(Ab, Bb, K, rmA)

    // epilogue: per i-band, stage 32 rows x 128 cols bf16 in LDS, then 16B/lane stores
    float bv[4];
#pragma unroll
    for (int j = 0; j < 4; ++j) bv[j] = bias[n0 + wn + j * 16 + r];

#pragma unroll
    for (int i = 0; i < 4; ++i) {
#pragma unroll
        for (int j = 0; j < 4; ++j) {
#pragma unroll
            for (int t2 = 0; t2 < 4; ++t2) {
                float v = acc[i][j][t2] + bv[j];
                v = v > 0.f ? v : NEG_SLOPE * v;
                Ep[(band * 16 + q * 4 + t2) * 128 + wn + j * 16 + r] = f2bf(v);
            }
        }
        __syncthreads();
#pragma unroll
        for (int rr = 0; rr < 2; ++rr) {
            int c = rr * 256 + tid;
            int lrow = c >> 4, ccol = c & 15;
            int grow = m0 + (lrow >> 4) * 64 + i * 16 + (lrow & 15);
            if (grow < M) {
                short8 v = *(const short8*)(Ep + lrow * 128 + ccol * 8);
                *(short8*)(C + (long)grow * D_HID + n0 + ccol * 8) = v;
            }
        }
        __syncthreads();
    }
}

// ---- GEMM2 fused with head: out[row] += sum_col leaky(A@Bt^T + b2) * wout[col] ----
__global__ __launch_bounds__(256) void k_gemm2f(const unsigned short* __restrict__ A,
                                                const unsigned short* __restrict__ Bt,
                                                const float* __restrict__ bias,
                                                const float* __restrict__ wout,
                                                float* __restrict__ out,
                                                int M, int K) {
    __shared__ __align__(16) unsigned short As[2][128 * 64];
    __shared__ __align__(16) unsigned short Bs[2][128 * 64];
    const int tid  = threadIdx.x;
    const int lane = tid & 63, wave = tid >> 6;
    int m0, n0;
    if (!map_block(blockIdx.x, M, m0, n0)) return;
    const int r = lane & 15, q = lane >> 4;
    const int xv = r & 7;
    const int wm = (wave & 1) * 64, wn = (wave >> 1) * 64;
    const int rmA = M - 1 - m0;
    const unsigned short* Ab = A + (long)m0 * K;
    const unsigned short* Bb = Bt + (long)n0 * K;

    floatx4 acc[4][4];
#pragma unroll
    for (int i = 0; i < 4; ++i)
#pragma unroll
        for (int j = 0; j < 4; ++j) acc[i][j] = (floatx4){0.f, 0.f, 0.f, 0.f};

    GEMM_KLOOP(Ab, Bb, K, rmA)

    float bv[4], wv[4];
#pragma unroll
    for (int j = 0; j < 4; ++j) {
        int col = n0 + wn + j * 16 + r;
        bv[j] = bias[col];
        wv[j] = wout[col];
    }
#pragma unroll
    for (int i = 0; i < 4; ++i) {
#pragma unroll
        for (int t2 = 0; t2 < 4; ++t2) {
            float p = 0.f;
#pragma unroll
            for (int j = 0; j < 4; ++j) {
                float v = acc[i][j][t2] + bv[j];
                v = v > 0.f ? v : NEG_SLOPE * v;
                p += v * wv[j];
            }
            p += __shfl_xor(p, 8, 64);
            p += __shfl_xor(p, 4, 64);
            p += __shfl_xor(p, 2, 64);
            p += __shfl_xor(p, 1, 64);
            if (r == 0) {
                int row = m0 + wm + i * 16 + q * 4 + t2;
                if (row < M) atomicAdd(&out[row], p);   // out pre-seeded with b_out
            }
        }
    }
}

extern "C" void kernel_launch(void* const* d_in, const int* in_sizes, int n_in,
                              void* d_out, int out_size, void* d_ws, size_t ws_size,
                              hipStream_t stream) {
    const float* x     = (const float*)d_in[0];
    const void*  ei    = d_in[1];
    const float* W_gcn = (const float*)d_in[2];
    const float* b_gcn = (const float*)d_in[3];
    const float* W2    = (const float*)d_in[4];
    const float* b2    = (const float*)d_in[5];
    const float* W_out = (const float*)d_in[6];
    const float* b_out = (const float*)d_in[7];
    float* out = (float*)d_out;

    const int N = in_sizes[0] / D_IN;
    const int E = in_sizes[1] / 2;

    char* w = (char*)d_ws;
    size_t off = 0;
    auto alloc = [&](size_t bytes) { char* p = w + off; off = (off + bytes + 255) & ~(size_t)255; return p; };
    int*            ovfcnt = (int*)alloc(256);
    int*            deg_i  = (int*)alloc((size_t)N * 4);
    int2*           ovf    = (int2*)alloc((size_t)OVF_MAX * 8);
    unsigned short* esrc   = (unsigned short*)alloc((size_t)N * CAP * 2);
    unsigned short* xb     = (unsigned short*)alloc((size_t)N * D_IN * 2);
    unsigned short* aggb   = (unsigned short*)alloc((size_t)N * D_IN * 2);
    unsigned short* h1     = (unsigned short*)alloc((size_t)N * D_HID * 2);
    unsigned short* Wgt    = (unsigned short*)alloc((size_t)D_IN * D_HID * 2);
    unsigned short* W2t    = (unsigned short*)alloc((size_t)D_HID * D_HID * 2);

    hipMemsetAsync(deg_i, 0, (size_t)N * 4, stream);
    hipMemsetAsync(ovfcnt, 0, 4, stream);

    int npairs = E < 2048 ? E : 2048;
    long xthreads = (long)N * D_IN / 4;
    int FB = (E + 255) / 256;
    int init_blocks = FB + 96 + (int)((xthreads + 255) / 256);
    k_initfill<<<init_blocks, 256, 0, stream>>>(x, xb, deg_i, N, ei, E, npairs,
                                                esrc, ovf, ovfcnt, b_out, out,
                                                W_gcn, Wgt, W2, W2t, xthreads, FB);

    k_gather<<<(N + 3) / 4, 256, 0, stream>>>(xb, deg_i, esrc, ovf, ovfcnt, aggb, N);

    int mtiles = (N + 127) / 128;
    int gblocks = ((mtiles + 7) / 8) * 8 * 4;
    k_gemm_bf16<<<gblocks, 256, 0, stream>>>(aggb, Wgt, b_gcn, h1, N, D_IN);
    k_gemm2f<<<gblocks, 256, 0, stream>>>(h1, W2t, b2, W_out, out, N, D_HID);
}

// Round 17
// 272.807 us; speedup vs baseline: 1.0293x; 1.0089x over previous
//
#include <hip/hip_runtime.h>

#define D_IN  256
#define D_HID 512
#define NEG_SLOPE 0.2f
#define CAP 32                 // bucket = 32 x u16 = 64 B = ONE line -> per-XCD scatter
                               // footprint ~2.8MB < 4MiB L2 (proven round 13). deg>32
                               // spills (~5-10 nodes) go to ovf; gather scans it ONLY
                               // when deg[node] > CAP (round-13 scanned unconditionally).
#define OVF_MAX 65536

typedef __attribute__((ext_vector_type(8))) short short8;
typedef __attribute__((ext_vector_type(4))) float floatx4;

__device__ __forceinline__ unsigned short f2bf(float f) {
    unsigned int u = __float_as_uint(f);
    u += 0x7fffu + ((u >> 16) & 1u);   // round-to-nearest-even
    return (unsigned short)(u >> 16);
}
__device__ __forceinline__ float bf2f(unsigned short u) {
    return __uint_as_float(((unsigned int)u) << 16);
}

__device__ __forceinline__ int eidx(const void* ei, long pos, int is64) {
    return is64 ? (int)((const long long*)ei)[pos] : ((const int*)ei)[pos];
}

// ---- merged init+degfill: blocks [0,FB) run the degfill atomic pass (long-latency,
//      launched first); blocks [FB,FB+96) do weight transposes; the rest stream
//      x->bf16 and seed out=b_out. deg/ovfcnt pre-zeroed via hipMemsetAsync. ----
__global__ __launch_bounds__(256) void k_initfill(const float* __restrict__ x,
                                                  unsigned short* __restrict__ xb,
                                                  int* __restrict__ deg, int N,
                                                  const void* __restrict__ ei, int E,
                                                  int npairs,
                                                  unsigned short* __restrict__ esrc,
                                                  int2* __restrict__ ovf,
                                                  int* __restrict__ ovfcnt,
                                                  const float* __restrict__ b_out,
                                                  float* __restrict__ out,
                                                  const float* __restrict__ Wa,
                                                  unsigned short* __restrict__ Wat,
                                                  const float* __restrict__ Wb,
                                                  unsigned short* __restrict__ Wbt,
                                                  long xthreads, int FB) {
    __shared__ float tl[64][65];
    int b = blockIdx.x;
    if (b < FB) {                      // degfill: deg-count + direct bucket scatter
        __shared__ int nz;
        if (threadIdx.x == 0) nz = 0;
        __syncthreads();
        const unsigned int* eu = (const unsigned int*)ei;
        for (int p = threadIdx.x; p < npairs; p += 256)
            if (eu[2 * p + 1] != 0) nz = 1;
        __syncthreads();
        int is64 = nz ? 0 : 1;
        int e = b * 256 + threadIdx.x;
        if (e >= E) return;
        int s = eidx(ei, e, is64), d = eidx(ei, (long)E + e, is64);
        int r = atomicAdd(&deg[d], 1);
        if (r < CAP) {
            esrc[d * CAP + r] = (unsigned short)s;   // N=50000 < 65536
        } else {
            int p = atomicAdd(ovfcnt, 1);
            if (p < OVF_MAX) ovf[p] = make_int2(d, s);
        }
        return;
    }
    b -= FB;
    if (b < 96) {                      // weight transpose, coalesced both ways
        const float* W; unsigned short* Wt; int K, Nc, tk, tn;
        if (b < 32) { W = Wa; Wt = Wat; K = 256; Nc = 512; tk = b & 3; tn = b >> 2; }
        else { b -= 32; W = Wb; Wt = Wbt; K = 512; Nc = 512; tk = b & 7; tn = b >> 3; }
        int k0 = tk * 64, n0 = tn * 64;
        int c = threadIdx.x & 63;
        int r0 = threadIdx.x >> 6;
#pragma unroll
        for (int i = 0; i < 16; ++i) {
            int r = r0 + i * 4;
            tl[r][c] = W[(long)(k0 + r) * Nc + n0 + c];
        }
        __syncthreads();
#pragma unroll
        for (int i = 0; i < 16; ++i) {
            int r = r0 + i * 4;
            Wt[(long)(n0 + r) * K + k0 + c] = f2bf(tl[c][r]);
        }
        return;
    }
    long t = (long)(b - 96) * 256 + threadIdx.x;
    if (t < xthreads) {                // 1 thread = 4 floats
        long i = t * 4;
        float4 v = *(const float4*)(x + i);
        ushort4 o;
        o.x = f2bf(v.x); o.y = f2bf(v.y); o.z = f2bf(v.z); o.w = f2bf(v.w);
        *(ushort4*)(xb + i) = o;
    }
    if (t < N) out[t] = b_out[0];      // gemm2f atomically adds on top
}

// ---- gather: wave=node, u16 bucketed edges; dinv on the fly (rsqrt of deg).
//      Overflow scan ONLY for spilled nodes (deg > CAP). ----
__global__ __launch_bounds__(256) void k_gather(const unsigned short* __restrict__ xb,
                                                const int* __restrict__ deg,
                                                const unsigned short* __restrict__ esrc,
                                                const int2* __restrict__ ovf,
                                                const int* __restrict__ ovfcnt,
                                                unsigned short* __restrict__ aggb, int N) {
    int node = blockIdx.x * 4 + (threadIdx.x >> 6);
    int lane = threadIdx.x & 63;
    if (node >= N) return;
    int half = lane >> 5;
    int li   = lane & 31;
    int colofs = li * 8;
    int dn = deg[node];
    float di = rsqrtf(1.0f + (float)dn);

    float a[8];
    {
        short8 v = *(const short8*)(xb + (long)node * D_IN + colofs);
#pragma unroll
        for (int j = 0; j < 8; ++j)
            a[j] = (half == 0) ? di * bf2f((unsigned short)v[j]) : 0.f;
    }

    int cnt = dn > CAP ? CAP : dn;
    int beg = node * CAP, end = beg + cnt;
    int e = beg;
    for (; e + 8 <= end; e += 8) {      // 4 x 1KB wave-loads in flight
        int s0 = esrc[e + half];
        int s1 = esrc[e + 2 + half];
        int s2 = esrc[e + 4 + half];
        int s3 = esrc[e + 6 + half];
        float w0 = rsqrtf(1.0f + (float)deg[s0]);
        float w1 = rsqrtf(1.0f + (float)deg[s1]);
        float w2 = rsqrtf(1.0f + (float)deg[s2]);
        float w3 = rsqrtf(1.0f + (float)deg[s3]);
        short8 u0 = *(const short8*)(xb + (long)s0 * D_IN + colofs);
        short8 u1 = *(const short8*)(xb + (long)s1 * D_IN + colofs);
        short8 u2 = *(const short8*)(xb + (long)s2 * D_IN + colofs);
        short8 u3 = *(const short8*)(xb + (long)s3 * D_IN + colofs);
#pragma unroll
        for (int j = 0; j < 8; ++j)
            a[j] += w0 * bf2f((unsigned short)u0[j]) + w1 * bf2f((unsigned short)u1[j])
                  + w2 * bf2f((unsigned short)u2[j]) + w3 * bf2f((unsigned short)u3[j]);
    }
    for (; e < end; e += 2) {
        int j0 = e + half;
        int jj = (j0 < end) ? j0 : end - 1;
        int s = esrc[jj];
        float w = (j0 < end) ? rsqrtf(1.0f + (float)deg[s]) : 0.f;
        short8 u = *(const short8*)(xb + (long)s * D_IN + colofs);
#pragma unroll
        for (int j = 0; j < 8; ++j)
            a[j] += w * bf2f((unsigned short)u[j]);
    }

    if (dn > CAP) {                    // spilled node: scan overflow list (L2-hot, ~10)
        int oc = *ovfcnt;
        if (oc > OVF_MAX) oc = OVF_MAX;
        for (int i = 0; i < oc; ++i) {
            int2 p = ovf[i];
            if (p.x == node && half == 0) {
                float w = rsqrtf(1.0f + (float)deg[p.y]);
                short8 u = *(const short8*)(xb + (long)p.y * D_IN + colofs);
#pragma unroll
                for (int j = 0; j < 8; ++j)
                    a[j] += w * bf2f((unsigned short)u[j]);
            }
        }
    }

#pragma unroll
    for (int j = 0; j < 8; ++j) a[j] += __shfl_xor(a[j], 32, 64);

    if (half == 0) {
        short8 o;
#pragma unroll
        for (int j = 0; j < 8; ++j) o[j] = (short)f2bf(a[j] * di);
        *(short8*)(aggb + (long)node * D_IN + colofs) = o;
    }
}

// ============ BK=64 swizzled-LDS 128x128 GEMM, counted-vmcnt 2-deep pipeline ======
__device__ __forceinline__ void async_cp16(const unsigned short* gp, unsigned short* lp) {
    __builtin_amdgcn_global_load_lds((const __attribute__((address_space(1))) void*)gp,
                                     (__attribute__((address_space(3))) void*)lp, 16, 0, 0);
}

__device__ __forceinline__ void stage_sw64(const unsigned short* src, int strideK,
                                           int rowMax, unsigned short* lds, int tid) {
#pragma unroll
    for (int rr = 0; rr < 4; ++rr) {
        int c = rr * 256 + tid;          // 0..1023 16B chunks
        int row = c >> 3;
        int ci = (c & 7) ^ (row & 7);    // logical chunk stored at this slot
        if (row > rowMax) row = rowMax;
        async_cp16(src + (long)row * strideK + ci * 8, lds + c * 8);
    }
}

__device__ __forceinline__ bool map_block(int b, int M, int& m0, int& n0) {
    int x = b & 7, slot = b >> 3;
    int mt = x + 8 * (slot >> 2);
    m0 = mt * 128; n0 = (slot & 3) * 128;
    return m0 < M;
}

__device__ __forceinline__ void mfma_step(const unsigned short* As_,
                                          const unsigned short* Bs_,
                                          floatx4 acc[4][4],
                                          int wm, int wn, int r, int q, int xv) {
#pragma unroll
    for (int s = 0; s < 2; ++s) {        // two K=32 sub-steps per tile
        int slotbase = s * 4 + q;
        short8 af[4], bf[4];
#pragma unroll
        for (int i = 0; i < 4; ++i)
            af[i] = *(const short8*)(As_ + (wm + i * 16 + r) * 64 + (slotbase ^ xv) * 8);
#pragma unroll
        for (int j = 0; j < 4; ++j)
            bf[j] = *(const short8*)(Bs_ + (wn + j * 16 + r) * 64 + (slotbase ^ xv) * 8);
#pragma unroll
        for (int i = 0; i < 4; ++i)
#pragma unroll
            for (int j = 0; j < 4; ++j)
                acc[i][j] = __builtin_amdgcn_mfma_f32_16x16x32_bf16(af[i], bf[j], acc[i][j], 0, 0, 0);
    }
}

// K-loop body shared by both GEMMs. 8 global_load_lds per thread per tile:
// vmcnt(8) == "my older tile has fully landed".
#define GEMM_KLOOP(Ab, Bb, K, rmA)                                              \
    const int nt = (K) >> 6;                                                    \
    stage_sw64((Ab), (K), (rmA), As[0], tid);                                   \
    stage_sw64((Bb), (K), 127, Bs[0], tid);                                     \
    if (nt > 1) {                                                               \
        stage_sw64((Ab) + 64, (K), (rmA), As[1], tid);                          \
        stage_sw64((Bb) + 64, (K), 127, Bs[1], tid);                            \
    }                                                                           \
    for (int t = 0; t < nt; ++t) {                                              \
        const int cur = t & 1;                                                  \
        if (t + 1 < nt) asm volatile("s_waitcnt vmcnt(8)" ::: "memory");        \
        else            asm volatile("s_waitcnt vmcnt(0)" ::: "memory");        \
        __builtin_amdgcn_sched_barrier(0);                                      \
        __builtin_amdgcn_s_barrier();                                           \
        __builtin_amdgcn_sched_barrier(0);                                      \
        mfma_step(As[cur], Bs[cur], acc, wm, wn, r, q, xv);                     \
        __builtin_amdgcn_sched_barrier(0);                                      \
        __builtin_amdgcn_s_barrier();                                           \
        __builtin_amdgcn_sched_barrier(0);                                      \
        if (t + 2 < nt) {                                                       \
            stage_sw64((Ab) + (long)(t + 2) * 64, (K), (rmA), As[cur], tid);    \
            stage_sw64((Bb) + (long)(t + 2) * 64, (K), 127, Bs[cur], tid);      \
        }                                                                       \
    }

// ---- GEMM1: C[M,512] = bf16(leaky(A[M,K] @ Bt[512,K]^T + bias)), LDS-staged store ----
__global__ __launch_bounds__(256) void k_gemm_bf16(const unsigned short* __restrict__ A,
                                                   const unsigned short* __restrict__ Bt,
                                                   const float* __restrict__ bias,
                                                   unsigned short* __restrict__ C,
                                                   int M, int K) {
    __shared__ __align__(16) unsigned short As[2][128 * 64];   // 32 KB
    __shared__ __align__(16) unsigned short Bs[2][128 * 64];   // 32 KB
    __shared__ __align__(16) unsigned short Ep[32 * 128];      // epilogue staging, 8 KB
    const int tid  = threadIdx.x;
    const int lane = tid & 63, wave = tid >> 6;
    int m0, n0;
    if (!map_block(blockIdx.x, M, m0, n0)) return;
    const int r = lane & 15, q = lane >> 4;
    const int xv = r & 7;
    const int wm = (wave & 1) * 64, wn = (wave >> 1) * 64;
    const int band = wm >> 6;
    const int rmA = M - 1 - m0;
    const unsigned short* Ab = A + (long)m0 * K;
    const unsigned short* Bb = Bt + (long)n0 * K;

    floatx4 acc[4][4];
#pragma unroll
    for (int i = 0; i < 4; ++i)
#pragma unroll
        for (int j = 0; j < 4; ++j) acc[i][j] = (floatx4){0.f, 0.f, 0.f, 0.f};

    GEMM_KLOOP(Ab, Bb, K, rmA)

    // epilogue: per i-band, stage 32 rows x 128 cols bf16 in LDS, then 16B/lane stores
    float bv[4];
#pragma unroll
    for (int j = 0; j < 4; ++j) bv[j] = bias[n0 + wn + j * 16 + r];

#pragma unroll
    for (int i = 0; i < 4; ++i) {
#pragma unroll
        for (int j = 0; j < 4; ++j) {
#pragma unroll
            for (int t2 = 0; t2 < 4; ++t2) {
                float v = acc[i][j][t2] + bv[j];
                v = v > 0.f ? v : NEG_SLOPE * v;
                Ep[(band * 16 + q * 4 + t2) * 128 + wn + j * 16 + r] = f2bf(v);
            }
        }
        __syncthreads();
#pragma unroll
        for (int rr = 0; rr < 2; ++rr) {
            int c = rr * 256 + tid;
            int lrow = c >> 4, ccol = c & 15;
            int grow = m0 + (lrow >> 4) * 64 + i * 16 + (lrow & 15);
            if (grow < M) {
                short8 v = *(const short8*)(Ep + lrow * 128 + ccol * 8);
                *(short8*)(C + (long)grow * D_HID + n0 + ccol * 8) = v;
            }
        }
        __syncthreads();
    }
}

// ---- GEMM2 fused with head: out[row] += sum_col leaky(A@Bt^T + b2) * wout[col] ----
__global__ __launch_bounds__(256) void k_gemm2f(const unsigned short* __restrict__ A,
                                                const unsigned short* __restrict__ Bt,
                                                const float* __restrict__ bias,
                                                const float* __restrict__ wout,
                                                float* __restrict__ out,
                                                int M, int K) {
    __shared__ __align__(16) unsigned short As[2][128 * 64];
    __shared__ __align__(16) unsigned short Bs[2][128 * 64];
    const int tid  = threadIdx.x;
    const int lane = tid & 63, wave = tid >> 6;
    int m0, n0;
    if (!map_block(blockIdx.x, M, m0, n0)) return;
    const int r = lane & 15, q = lane >> 4;
    const int xv = r & 7;
    const int wm = (wave & 1) * 64, wn = (wave >> 1) * 64;
    const int rmA = M - 1 - m0;
    const unsigned short* Ab = A + (long)m0 * K;
    const unsigned short* Bb = Bt + (long)n0 * K;

    floatx4 acc[4][4];
#pragma unroll
    for (int i = 0; i < 4; ++i)
#pragma unroll
        for (int j = 0; j < 4; ++j) acc[i][j] = (floatx4){0.f, 0.f, 0.f, 0.f};

    GEMM_KLOOP(Ab, Bb, K, rmA)

    float bv[4], wv[4];
#pragma unroll
    for (int j = 0; j < 4; ++j) {
        int col = n0 + wn + j * 16 + r;
        bv[j] = bias[col];
        wv[j] = wout[col];
    }
#pragma unroll
    for (int i = 0; i < 4; ++i) {
#pragma unroll
        for (int t2 = 0; t2 < 4; ++t2) {
            float p = 0.f;
#pragma unroll
            for (int j = 0; j < 4; ++j) {
                float v = acc[i][j][t2] + bv[j];
                v = v > 0.f ? v : NEG_SLOPE * v;
                p += v * wv[j];
            }
            p += __shfl_xor(p, 8, 64);
            p += __shfl_xor(p, 4, 64);
            p += __shfl_xor(p, 2, 64);
            p += __shfl_xor(p, 1, 64);
            if (r == 0) {
                int row = m0 + wm + i * 16 + q * 4 + t2;
                if (row < M) atomicAdd(&out[row], p);   // out pre-seeded with b_out
            }
        }
    }
}

extern "C" void kernel_launch(void* const* d_in, const int* in_sizes, int n_in,
                              void* d_out, int out_size, void* d_ws, size_t ws_size,
                              hipStream_t stream) {
    const float* x     = (const float*)d_in[0];
    const void*  ei    = d_in[1];
    const float* W_gcn = (const float*)d_in[2];
    const float* b_gcn = (const float*)d_in[3];
    const float* W2    = (const float*)d_in[4];
    const float* b2    = (const float*)d_in[5];
    const float* W_out = (const float*)d_in[6];
    const float* b_out = (const float*)d_in[7];
    float* out = (float*)d_out;

    const int N = in_sizes[0] / D_IN;
    const int E = in_sizes[1] / 2;

    char* w = (char*)d_ws;
    size_t off = 0;
    auto alloc = [&](size_t bytes) { char* p = w + off; off = (off + bytes + 255) & ~(size_t)255; return p; };
    int*            ovfcnt = (int*)alloc(256);
    int*            deg_i  = (int*)alloc((size_t)N * 4);
    int2*           ovf    = (int2*)alloc((size_t)OVF_MAX * 8);
    unsigned short* esrc   = (unsigned short*)alloc((size_t)N * CAP * 2);
    unsigned short* xb     = (unsigned short*)alloc((size_t)N * D_IN * 2);
    unsigned short* aggb   = (unsigned short*)alloc((size_t)N * D_IN * 2);
    unsigned short* h1     = (unsigned short*)alloc((size_t)N * D_HID * 2);
    unsigned short* Wgt    = (unsigned short*)alloc((size_t)D_IN * D_HID * 2);
    unsigned short* W2t    = (unsigned short*)alloc((size_t)D_HID * D_HID * 2);

    hipMemsetAsync(deg_i, 0, (size_t)N * 4, stream);
    hipMemsetAsync(ovfcnt, 0, 4, stream);

    int npairs = E < 2048 ? E : 2048;
    long xthreads = (long)N * D_IN / 4;
    int FB = (E + 255) / 256;
    int init_blocks = FB + 96 + (int)((xthreads + 255) / 256);
    k_initfill<<<init_blocks, 256, 0, stream>>>(x, xb, deg_i, N, ei, E, npairs,
                                                esrc, ovf, ovfcnt, b_out, out,
                                                W_gcn, Wgt, W2, W2t, xthreads, FB);

    k_gather<<<(N + 3) / 4, 256, 0, stream>>>(xb, deg_i, esrc, ovf, ovfcnt, aggb, N);

    int mtiles = (N + 127) / 128;
    int gblocks = ((mtiles + 7) / 8) * 8 * 4;
    k_gemm_bf16<<<gblocks, 256, 0, stream>>>(aggb, Wgt, b_gcn, h1, N, D_IN);
    k_gemm2f<<<gblocks, 256, 0, stream>>>(h1, W2t, b2, W_out, out, N, D_HID);
}